// Round 4
// baseline (3342.342 us; speedup 1.0000x reference)
//
#include <hip/hip_runtime.h>
#include <cfloat>
#include <climits>

#define NPTS 8192
#define NDIM 64
#define NB   2
#define KK   16
#define NROWS (NB * NPTS)

typedef float f2 __attribute__((ext_vector_type(2)));

// ---------- numpy f32 sum model: AVX512 pairwise(64) + reduce_add tree ----
__device__ __forceinline__ float np_sum64(const float* v) {
#pragma clang fp contract(off)
    float L[16], M[8], P[4];
#pragma unroll
    for (int l = 0; l < 16; ++l)
        L[l] = __fadd_rn(__fadd_rn(v[l], v[16 + l]), __fadd_rn(v[32 + l], v[48 + l]));
#pragma unroll
    for (int l = 0; l < 8; ++l) M[l] = __fadd_rn(L[l], L[l + 8]);
#pragma unroll
    for (int l = 0; l < 4; ++l) P[l] = __fadd_rn(M[l], M[l + 4]);
    return __fadd_rn(__fadd_rn(P[0], P[2]), __fadd_rn(P[1], P[3]));
}

// ---------- prep: s[] via np model; xTp pair-interleaved transpose --------
// element (n, c) stored at (n&~1)*64 + 2*c + (n&1)  => candidate pairs are
// adjacent 8B units, enabling packed-f32 (v_pk_*) in k_main.
__global__ __launch_bounds__(256) void k_prep(const float* __restrict__ x,
                                              float* __restrict__ s,
                                              float* __restrict__ xTp) {
#pragma clang fp contract(off)
    int g = blockIdx.x * 256 + threadIdx.x;       // 0 .. NROWS-1
    int b = g / NPTS, n = g % NPTS;
    const float* xb = x + (size_t)b * NDIM * NPTS + n;
    float a[NDIM], v[NDIM];
#pragma unroll
    for (int c = 0; c < NDIM; ++c) {
        a[c] = xb[(size_t)c * NPTS];
        v[c] = __fmul_rn(a[c], a[c]);
    }
    s[g] = np_sum64(v);
    float* dst = xTp + ((size_t)(b * NPTS + (n & ~1))) * NDIM + (n & 1);
#pragma unroll
    for (int c = 0; c < NDIM; ++c) dst[2 * c] = a[c];
}

// ---------- main: packed dot chains + deferred LDS top-16 selection -------
__global__ __launch_bounds__(256, 4) void k_main(const float* __restrict__ x,
                                                 const float* __restrict__ xTp,
                                                 const float* __restrict__ s,
                                                 float* __restrict__ wd,
                                                 int* __restrict__ wi,
                                                 int js, int jlen) {
#pragma clang fp contract(off)
#pragma clang fp reassociate(off)
    const int tid   = threadIdx.x;
    const int bi    = blockIdx.x & 63;   // b*32 + itile
    const int chunk = blockIdx.x >> 6;
    const int b     = bi >> 5;
    const int itile = bi & 31;
    const int i     = itile * 256 + tid;
    const int boff  = b * NPTS;

    // per-thread deferred-candidate buffer, k-major: slot k of thread t at
    // buf[k*256+t] -> bank = (t*2)&31, conflict-free (2-way b64, free).
    __shared__ float2 buf[16 * 256];     // 32 KB

    const float* xb = x + (size_t)b * NDIM * NPTS + i;
    float a[NDIM];
#pragma unroll
    for (int c = 0; c < NDIM; ++c) a[c] = xb[(size_t)c * NPTS];
    const float si = s[boff + i];

    float ld[KK]; int li[KK];
#pragma unroll
    for (int e = 0; e < KK; ++e) { ld[e] = FLT_MAX; li[e] = INT_MAX; }
    float ldL = FLT_MAX;
    int   cnt = 0;

    const int j0 = chunk * jlen;
    for (int jt = 0; jt < jlen; jt += 16) {
#pragma unroll
        for (int gq = 0; gq < 2; ++gq) {
            const int j8 = j0 + jt + gq * 8;
            const f2* pb = (const f2*)(xTp + ((size_t)(boff + j8)) * NDIM);
            f2 A0 = {0.f, 0.f}, A1 = {0.f, 0.f}, A2 = {0.f, 0.f}, A3 = {0.f, 0.f};
#pragma unroll
            for (int c = 0; c < NDIM; ++c) {
                f2 av = {a[c], a[c]};
                A0 = A0 + av * pb[c];
                A1 = A1 + av * pb[NDIM + c];
                A2 = A2 + av * pb[2 * NDIM + c];
                A3 = A3 + av * pb[3 * NDIM + c];
            }
            const f2* s2 = (const f2*)(s + boff + j8);
            const f2 m2  = {-2.f, -2.f};
            const f2 si2 = {si, si};
            f2 D0 = (si2 + m2 * A0) + s2[0];
            f2 D1 = (si2 + m2 * A1) + s2[1];
            f2 D2 = (si2 + m2 * A2) + s2[2];
            f2 D3 = (si2 + m2 * A3) + s2[3];
            float dv[8] = {D0.x, D0.y, D1.x, D1.y, D2.x, D2.y, D3.x, D3.y};
#pragma unroll
            for (int q = 0; q < 8; ++q) {
                if (dv[q] < ldL) {           // strict <: equal-d later-j loses (stable)
                    buf[cnt * 256 + tid] = make_float2(dv[q], __int_as_float(j8 + q));
                    cnt++;
                }
            }
        }
        // drain: process buffered candidates in push (= ascending-j) order
        if (__any(cnt > 0)) {
            for (int k = 0; k < cnt; ++k) {
                float2 e = buf[k * 256 + tid];
                float cd = e.x; int ci = __float_as_int(e.y);
                if (cd < ldL) {
#pragma unroll
                    for (int t = 0; t < KK; ++t) {
                        bool sw = cd < ld[t];
                        float od = ld[t]; int oi = li[t];
                        ld[t] = sw ? cd : od;  li[t] = sw ? ci : oi;
                        cd    = sw ? od : cd;  ci    = sw ? oi : ci;
                    }
                    ldL = ld[KK - 1];
                }
            }
            cnt = 0;
        }
    }

    // transposed write: entry e of row g at wd[(chunk*16+e)*NROWS + g] (coalesced)
    const int g = boff + i;
#pragma unroll
    for (int e = 0; e < KK; ++e) {
        wd[(size_t)(chunk * KK + e) * NROWS + g] = ld[e];
        wi[(size_t)(chunk * KK + e) * NROWS + g] = li[e];
    }
}

// ---------- merge chunks by (d, idx) lex, write outputs --------------------
__global__ __launch_bounds__(256) void k_merge(const float* __restrict__ wd,
                                               const int* __restrict__ wi,
                                               int* __restrict__ out,
                                               int js) {
    int g = blockIdx.x * 256 + threadIdx.x;   // 0 .. NROWS-1
    int i = g % NPTS;

    float md[KK]; int mi[KK];
#pragma unroll
    for (int e = 0; e < KK; ++e) { md[e] = FLT_MAX; mi[e] = INT_MAX; }

    const int tot = js * KK;
    for (int t = 0; t < tot; ++t) {
        float d  = wd[(size_t)t * NROWS + g];
        int   ix = wi[(size_t)t * NROWS + g];
        bool better = (d < md[KK - 1]) || (d == md[KK - 1] && ix < mi[KK - 1]);
        if (better) {
            float cd = d; int ci = ix;
#pragma unroll
            for (int e = 0; e < KK; ++e) {
                bool sw = (cd < md[e]) || (cd == md[e] && ci < mi[e]);
                float od = md[e]; int oi = mi[e];
                md[e] = sw ? cd : od;  mi[e] = sw ? ci : oi;
                cd    = sw ? od : cd;  ci    = sw ? oi : ci;
            }
        }
    }

    const size_t ob = (size_t)g * KK;
#pragma unroll
    for (int e = 0; e < KK; ++e) {
        out[ob + e] = mi[e];                                  // nn_idx
        out[(size_t)NROWS * KK + ob + e] = i;                 // center_idx
    }
}

extern "C" void kernel_launch(void* const* d_in, const int* in_sizes, int n_in,
                              void* d_out, int out_size, void* d_ws, size_t ws_size,
                              hipStream_t stream) {
    const float* x = (const float*)d_in[0];
    int* out = (int*)d_out;

    const size_t S_BYTES  = 65536;                           // s: 16384 f32
    const size_t XT_BYTES = (size_t)NROWS * NDIM * 4;        // 4 MB

    int js = 16;
    while (js > 1) {
        size_t need = S_BYTES + XT_BYTES + (size_t)NROWS * js * KK * 8;
        if (need <= ws_size) break;
        js >>= 1;
    }
    float* s   = (float*)d_ws;
    float* xTp = (float*)((char*)d_ws + S_BYTES);
    float* wd  = (float*)((char*)d_ws + S_BYTES + XT_BYTES);
    int*   wi  = (int*)((char*)d_ws + S_BYTES + XT_BYTES + (size_t)NROWS * js * KK * 4);
    const int jlen = NPTS / js;

    k_prep <<<NROWS / 256, 256, 0, stream>>>(x, s, xTp);
    k_main <<<64 * js, 256, 0, stream>>>(x, xTp, s, wd, wi, js, jlen);
    k_merge<<<NROWS / 256, 256, 0, stream>>>(wd, wi, out, js);
}

// Round 5
// 1506.757 us; speedup vs baseline: 2.2182x; 2.2182x over previous
//
#include <hip/hip_runtime.h>
#include <cfloat>
#include <climits>

#define NPTS 8192
#define NDIM 64
#define NB   2
#define KK   16
#define NROWS (NB * NPTS)

typedef float f2 __attribute__((ext_vector_type(2)));

// ---------- numpy f32 sum model: AVX512 pairwise(64) + reduce_add tree ----
__device__ __forceinline__ float np_sum64(const float* v) {
#pragma clang fp contract(off)
    float L[16], M[8], P[4];
#pragma unroll
    for (int l = 0; l < 16; ++l)
        L[l] = __fadd_rn(__fadd_rn(v[l], v[16 + l]), __fadd_rn(v[32 + l], v[48 + l]));
#pragma unroll
    for (int l = 0; l < 8; ++l) M[l] = __fadd_rn(L[l], L[l + 8]);
#pragma unroll
    for (int l = 0; l < 4; ++l) P[l] = __fadd_rn(M[l], M[l + 4]);
    return __fadd_rn(__fadd_rn(P[0], P[2]), __fadd_rn(P[1], P[3]));
}

// ---------- prep: s[] via np model; xTp pair-interleaved transpose --------
// element (n, c) at (n&~1)*64 + 2*c + (n&1): candidate pairs adjacent 8B,
// enabling packed-f32 (v_pk_*) in k_main. Elementwise IEEE RN -> bit-exact.
__global__ __launch_bounds__(256) void k_prep(const float* __restrict__ x,
                                              float* __restrict__ s,
                                              float* __restrict__ xTp) {
#pragma clang fp contract(off)
    int g = blockIdx.x * 256 + threadIdx.x;       // 0 .. NROWS-1
    int b = g / NPTS, n = g % NPTS;
    const float* xb = x + (size_t)b * NDIM * NPTS + n;
    float a[NDIM], v[NDIM];
#pragma unroll
    for (int c = 0; c < NDIM; ++c) {
        a[c] = xb[(size_t)c * NPTS];
        v[c] = __fmul_rn(a[c], a[c]);
    }
    s[g] = np_sum64(v);
    float* dst = xTp + ((size_t)(b * NPTS + (n & ~1))) * NDIM + (n & 1);
#pragma unroll
    for (int c = 0; c < NDIM; ++c) dst[2 * c] = a[c];
}

// ---------- main: packed dot chains + deferred LDS top-16 selection -------
// NO min-occupancy hint: a[64]+ld[16]+li[16]+temps must live in VGPRs
// (~125). R4's __launch_bounds__(256,4) forced a 64-VGPR allocation ->
// scratch spill -> 8.4 GB HBM scratch traffic. Guideline 6.
__global__ __launch_bounds__(256) void k_main(const float* __restrict__ x,
                                              const float* __restrict__ xTp,
                                              const float* __restrict__ s,
                                              float* __restrict__ wd,
                                              int* __restrict__ wi,
                                              int js, int jlen) {
#pragma clang fp contract(off)
#pragma clang fp reassociate(off)
    const int tid = threadIdx.x;

    // XCD-aware mapping: dispatcher round-robins blockIdx over 8 XCDs
    // (m09). Put all 32 itile-blocks of one (b,chunk) group on ONE XCD so
    // its 128 KB xTp region is L2-resident there (4 groups x 128 KB = 512
    // KB per XCD). Perf heuristic only; any bijection is correct.
    const int ngroups = NB * js;
    int group, itile;
    if ((ngroups & 7) == 0) {
        const int gpx  = ngroups >> 3;      // groups per XCD
        const int xcd  = blockIdx.x & 7;
        const int slot = blockIdx.x >> 3;
        group = xcd * gpx + (slot >> 5);
        itile = slot & 31;
    } else {
        group = blockIdx.x >> 5;
        itile = blockIdx.x & 31;
    }
    const int b     = group / js;
    const int chunk = group - b * js;
    const int i     = itile * 256 + tid;
    const int boff  = b * NPTS;

    // per-thread deferred-candidate buffer, k-major: slot k of thread t at
    // buf[k*256+t]; hot loop does cmp + predicated push only, the 16-deep
    // sort runs per buffered entry at window drain (cost ~ actual inserts,
    // not wave-any).
    __shared__ float2 buf[16 * 256];     // 32 KB

    const float* xb = x + (size_t)b * NDIM * NPTS + i;
    float a[NDIM];
#pragma unroll
    for (int c = 0; c < NDIM; ++c) a[c] = xb[(size_t)c * NPTS];
    const float si = s[boff + i];

    float ld[KK]; int li[KK];
#pragma unroll
    for (int e = 0; e < KK; ++e) { ld[e] = FLT_MAX; li[e] = INT_MAX; }
    float ldL = FLT_MAX;
    int   cnt = 0;

    const int j0 = chunk * jlen;
    for (int jt = 0; jt < jlen; jt += 16) {
#pragma unroll
        for (int gq = 0; gq < 2; ++gq) {
            const int j8 = j0 + jt + gq * 8;
            const f2* pb = (const f2*)(xTp + ((size_t)(boff + j8)) * NDIM);
            f2 A0 = {0.f, 0.f}, A1 = {0.f, 0.f}, A2 = {0.f, 0.f}, A3 = {0.f, 0.f};
#pragma unroll
            for (int c = 0; c < NDIM; ++c) {
                f2 av = {a[c], a[c]};
                A0 = A0 + av * pb[c];
                A1 = A1 + av * pb[NDIM + c];
                A2 = A2 + av * pb[2 * NDIM + c];
                A3 = A3 + av * pb[3 * NDIM + c];
            }
            const f2* s2 = (const f2*)(s + boff + j8);
            const f2 m2  = {-2.f, -2.f};
            const f2 si2 = {si, si};
            // push immediately per pair (no staging array -> lower liveness)
#pragma unroll
            for (int p = 0; p < 4; ++p) {
                f2 A = (p == 0) ? A0 : (p == 1) ? A1 : (p == 2) ? A2 : A3;
                f2 D = (si2 + m2 * A) + s2[p];
                if (D.x < ldL) {         // strict <: equal-d later-j loses
                    buf[cnt * 256 + tid] = make_float2(D.x, __int_as_float(j8 + 2 * p));
                    cnt++;
                }
                if (D.y < ldL) {
                    buf[cnt * 256 + tid] = make_float2(D.y, __int_as_float(j8 + 2 * p + 1));
                    cnt++;
                }
            }
        }
        // drain: buffered candidates in push (= ascending-j) order
        if (__any(cnt > 0)) {
            for (int k = 0; k < cnt; ++k) {
                float2 e = buf[k * 256 + tid];
                float cd = e.x; int ci = __float_as_int(e.y);
                if (cd < ldL) {
#pragma unroll
                    for (int t = 0; t < KK; ++t) {
                        bool sw = cd < ld[t];
                        float od = ld[t]; int oi = li[t];
                        ld[t] = sw ? cd : od;  li[t] = sw ? ci : oi;
                        cd    = sw ? od : cd;  ci    = sw ? oi : ci;
                    }
                    ldL = ld[KK - 1];
                }
            }
            cnt = 0;
        }
    }

    // transposed write: entry e of row g at wd[(chunk*16+e)*NROWS + g] (coalesced)
    const int gg = boff + i;
#pragma unroll
    for (int e = 0; e < KK; ++e) {
        wd[(size_t)(chunk * KK + e) * NROWS + gg] = ld[e];
        wi[(size_t)(chunk * KK + e) * NROWS + gg] = li[e];
    }
}

// ---------- merge chunks by (d, idx) lex, write outputs --------------------
__global__ __launch_bounds__(256) void k_merge(const float* __restrict__ wd,
                                               const int* __restrict__ wi,
                                               int* __restrict__ out,
                                               int js) {
    int g = blockIdx.x * 256 + threadIdx.x;   // 0 .. NROWS-1
    int i = g % NPTS;

    float md[KK]; int mi[KK];
#pragma unroll
    for (int e = 0; e < KK; ++e) { md[e] = FLT_MAX; mi[e] = INT_MAX; }

    const int tot = js * KK;
    for (int t = 0; t < tot; ++t) {
        float d  = wd[(size_t)t * NROWS + g];
        int   ix = wi[(size_t)t * NROWS + g];
        bool better = (d < md[KK - 1]) || (d == md[KK - 1] && ix < mi[KK - 1]);
        if (better) {
            float cd = d; int ci = ix;
#pragma unroll
            for (int e = 0; e < KK; ++e) {
                bool sw = (cd < md[e]) || (cd == md[e] && ci < mi[e]);
                float od = md[e]; int oi = mi[e];
                md[e] = sw ? cd : od;  mi[e] = sw ? ci : oi;
                cd    = sw ? od : cd;  ci    = sw ? oi : ci;
            }
        }
    }

    const size_t ob = (size_t)g * KK;
#pragma unroll
    for (int e = 0; e < KK; ++e) {
        out[ob + e] = mi[e];                                  // nn_idx
        out[(size_t)NROWS * KK + ob + e] = i;                 // center_idx
    }
}

extern "C" void kernel_launch(void* const* d_in, const int* in_sizes, int n_in,
                              void* d_out, int out_size, void* d_ws, size_t ws_size,
                              hipStream_t stream) {
    const float* x = (const float*)d_in[0];
    int* out = (int*)d_out;

    const size_t S_BYTES  = 65536;                           // s: 16384 f32
    const size_t XT_BYTES = (size_t)NROWS * NDIM * 4;        // 4 MB

    int js = 16;
    while (js > 1) {
        size_t need = S_BYTES + XT_BYTES + (size_t)NROWS * js * KK * 8;
        if (need <= ws_size) break;
        js >>= 1;
    }
    float* s   = (float*)d_ws;
    float* xTp = (float*)((char*)d_ws + S_BYTES);
    float* wd  = (float*)((char*)d_ws + S_BYTES + XT_BYTES);
    int*   wi  = (int*)((char*)d_ws + S_BYTES + XT_BYTES + (size_t)NROWS * js * KK * 4);
    const int jlen = NPTS / js;

    k_prep <<<NROWS / 256, 256, 0, stream>>>(x, s, xTp);
    k_main <<<NB * js * 32, 256, 0, stream>>>(x, xTp, s, wd, wi, js, jlen);
    k_merge<<<NROWS / 256, 256, 0, stream>>>(wd, wi, out, js);
}

// Round 6
// 1121.564 us; speedup vs baseline: 2.9801x; 1.3434x over previous
//
#include <hip/hip_runtime.h>
#include <cfloat>
#include <climits>

#define NPTS 8192
#define NDIM 64
#define NB   2
#define KK   16
#define NROWS (NB * NPTS)

typedef float f2 __attribute__((ext_vector_type(2)));

// ---------- numpy f32 sum model: AVX512 pairwise(64) + reduce_add tree ----
__device__ __forceinline__ float np_sum64(const float* v) {
#pragma clang fp contract(off)
    float L[16], M[8], P[4];
#pragma unroll
    for (int l = 0; l < 16; ++l)
        L[l] = __fadd_rn(__fadd_rn(v[l], v[16 + l]), __fadd_rn(v[32 + l], v[48 + l]));
#pragma unroll
    for (int l = 0; l < 8; ++l) M[l] = __fadd_rn(L[l], L[l + 8]);
#pragma unroll
    for (int l = 0; l < 4; ++l) P[l] = __fadd_rn(M[l], M[l + 4]);
    return __fadd_rn(__fadd_rn(P[0], P[2]), __fadd_rn(P[1], P[3]));
}

// ---------- prep: s[] via np model; xTp pair-interleaved transpose --------
// element (n, c) at (n&~1)*64 + 2*c + (n&1): candidate pairs adjacent 8B.
__global__ __launch_bounds__(256) void k_prep(const float* __restrict__ x,
                                              float* __restrict__ s,
                                              float* __restrict__ xTp) {
#pragma clang fp contract(off)
    int g = blockIdx.x * 256 + threadIdx.x;       // 0 .. NROWS-1
    int b = g / NPTS, n = g % NPTS;
    const float* xb = x + (size_t)b * NDIM * NPTS + n;
    float a[NDIM], v[NDIM];
#pragma unroll
    for (int c = 0; c < NDIM; ++c) {
        a[c] = xb[(size_t)c * NPTS];
        v[c] = __fmul_rn(a[c], a[c]);
    }
    s[g] = np_sum64(v);
    float* dst = xTp + ((size_t)(b * NPTS + (n & ~1))) * NDIM + (n & 1);
#pragma unroll
    for (int c = 0; c < NDIM; ++c) dst[2 * c] = a[c];
}

// pk helpers: IEEE-RN elementwise packed f32 (VOP3P). op_sel broadcasts
// the chosen half of src0 to both result elements -> no broadcast movs.
__device__ __forceinline__ f2 pk_mul_blo(f2 a, f2 b) {   // {a.x*b.x, a.x*b.y}
    f2 t;
    asm("v_pk_mul_f32 %0, %1, %2 op_sel:[0,0] op_sel_hi:[0,1]"
        : "=v"(t) : "v"(a), "v"(b));
    return t;
}
__device__ __forceinline__ f2 pk_mul_bhi(f2 a, f2 b) {   // {a.y*b.x, a.y*b.y}
    f2 t;
    asm("v_pk_mul_f32 %0, %1, %2 op_sel:[1,0] op_sel_hi:[1,1]"
        : "=v"(t) : "v"(a), "v"(b));
    return t;
}
__device__ __forceinline__ void pk_acc(f2& A, f2 t) {    // A += t (elementwise)
    asm("v_pk_add_f32 %0, %0, %1" : "+v"(A) : "v"(t));
}

// ---------- main: asm-packed dot chains + deferred LDS top-16 selection ---
// hipcc scalarizes <2 x float> strict-FP arithmetic (R5: VALU-issue time
// identical to scalar R3) -> force v_pk_* via inline asm. Guideline 6: no
// min-occupancy hint (R4's (256,4) caused 64-VGPR spill, 8.4 GB scratch).
__global__ __launch_bounds__(256) void k_main(const float* __restrict__ x,
                                              const float* __restrict__ xTp,
                                              const float* __restrict__ s,
                                              float* __restrict__ wd,
                                              int* __restrict__ wi,
                                              int js, int jlen) {
#pragma clang fp contract(off)
    const int tid = threadIdx.x;

    // XCD-aware mapping: all 32 itile-blocks of one (b,chunk) group on one
    // XCD -> its 128 KB xTp slice is L2-resident (4 groups x 128 KB / XCD).
    const int ngroups = NB * js;
    int group, itile;
    if ((ngroups & 7) == 0) {
        const int gpx  = ngroups >> 3;
        const int xcd  = blockIdx.x & 7;
        const int slot = blockIdx.x >> 3;
        group = xcd * gpx + (slot >> 5);
        itile = slot & 31;
    } else {
        group = blockIdx.x >> 5;
        itile = blockIdx.x & 31;
    }
    const int b     = group / js;
    const int chunk = group - b * js;
    const int i     = itile * 256 + tid;
    const int boff  = b * NPTS;

    // deferred-candidate buffer, k-major, stride 257 (divergent-cnt pushes
    // land in different banks). Hot loop: cmp + predicated push only.
    __shared__ float2 buf[8 * 257];      // 16.4 KB

    const float* xb = x + (size_t)b * NDIM * NPTS + i;
    f2 a2[NDIM / 2];                     // {a[2q], a[2q+1]} pairs, 64 VGPRs
#pragma unroll
    for (int q = 0; q < NDIM / 2; ++q) {
        a2[q].x = xb[(size_t)(2 * q) * NPTS];
        a2[q].y = xb[(size_t)(2 * q + 1) * NPTS];
    }
    const float si = s[boff + i];

    float ld[KK]; int li[KK];
#pragma unroll
    for (int e = 0; e < KK; ++e) { ld[e] = FLT_MAX; li[e] = INT_MAX; }
    float ldL = FLT_MAX;
    int   cnt = 0;

    const int j0 = chunk * jlen;
#pragma unroll 1
    for (int jt = 0; jt < jlen; jt += 8) {        // window = 8 candidates
#pragma unroll
        for (int g4 = 0; g4 < 2; ++g4) {          // 2 groups x 4 cands
            const int j4 = j0 + jt + g4 * 4;
            const f2* p0 = (const f2*)(xTp + (size_t)(boff + j4) * NDIM);
            const f2* p1 = p0 + NDIM;             // next pair (j4+2, j4+3)
            f2 A0 = {0.f, 0.f}, A1 = {0.f, 0.f};
#pragma unroll
            for (int q = 0; q < NDIM / 2; ++q) {
                f2 aq  = a2[q];
                f2 b0l = p0[2 * q], b0h = p0[2 * q + 1];
                f2 b1l = p1[2 * q], b1h = p1[2 * q + 1];
                // ascending-c sequential adds per chain: bit-exact np chain
                pk_acc(A0, pk_mul_blo(aq, b0l));   // c = 2q
                pk_acc(A1, pk_mul_blo(aq, b1l));
                pk_acc(A0, pk_mul_bhi(aq, b0h));   // c = 2q+1
                pk_acc(A1, pk_mul_bhi(aq, b1h));
            }
            // epilogue: (si + (-2*dot)) + s_j, scalar RN (bit-exact chain)
            const float* sj = s + boff + j4;
            float d0 = __fadd_rn(__fadd_rn(si, __fmul_rn(-2.0f, A0.x)), sj[0]);
            float d1 = __fadd_rn(__fadd_rn(si, __fmul_rn(-2.0f, A0.y)), sj[1]);
            float d2 = __fadd_rn(__fadd_rn(si, __fmul_rn(-2.0f, A1.x)), sj[2]);
            float d3 = __fadd_rn(__fadd_rn(si, __fmul_rn(-2.0f, A1.y)), sj[3]);
            // strict <: equal-d later-j loses (stable); push ascending-j
            if (d0 < ldL) { buf[cnt * 257 + tid] = make_float2(d0, __int_as_float(j4 + 0)); cnt++; }
            if (d1 < ldL) { buf[cnt * 257 + tid] = make_float2(d1, __int_as_float(j4 + 1)); cnt++; }
            if (d2 < ldL) { buf[cnt * 257 + tid] = make_float2(d2, __int_as_float(j4 + 2)); cnt++; }
            if (d3 < ldL) { buf[cnt * 257 + tid] = make_float2(d3, __int_as_float(j4 + 3)); cnt++; }
        }
        // drain buffered candidates in push (= ascending-j) order
        if (__any(cnt > 0)) {
            for (int k = 0; k < cnt; ++k) {
                float2 e = buf[k * 257 + tid];
                float cd = e.x; int ci = __float_as_int(e.y);
                if (cd < ldL) {
#pragma unroll
                    for (int t = 0; t < KK; ++t) {
                        bool sw = cd < ld[t];
                        float od = ld[t]; int oi = li[t];
                        ld[t] = sw ? cd : od;  li[t] = sw ? ci : oi;
                        cd    = sw ? od : cd;  ci    = sw ? oi : ci;
                    }
                    ldL = ld[KK - 1];
                }
            }
            cnt = 0;
        }
    }

    // transposed write: entry e of row g at wd[(chunk*16+e)*NROWS+g] (coalesced)
    const int gg = boff + i;
#pragma unroll
    for (int e = 0; e < KK; ++e) {
        wd[(size_t)(chunk * KK + e) * NROWS + gg] = ld[e];
        wi[(size_t)(chunk * KK + e) * NROWS + gg] = li[e];
    }
}

// ---------- merge chunks by (d, idx) lex, write outputs --------------------
__global__ __launch_bounds__(256) void k_merge(const float* __restrict__ wd,
                                               const int* __restrict__ wi,
                                               int* __restrict__ out,
                                               int js) {
    int g = blockIdx.x * 256 + threadIdx.x;   // 0 .. NROWS-1
    int i = g % NPTS;

    float md[KK]; int mi[KK];
#pragma unroll
    for (int e = 0; e < KK; ++e) { md[e] = FLT_MAX; mi[e] = INT_MAX; }

    const int tot = js * KK;
    for (int t = 0; t < tot; ++t) {
        float d  = wd[(size_t)t * NROWS + g];
        int   ix = wi[(size_t)t * NROWS + g];
        bool better = (d < md[KK - 1]) || (d == md[KK - 1] && ix < mi[KK - 1]);
        if (better) {
            float cd = d; int ci = ix;
#pragma unroll
            for (int e = 0; e < KK; ++e) {
                bool sw = (cd < md[e]) || (cd == md[e] && ci < mi[e]);
                float od = md[e]; int oi = mi[e];
                md[e] = sw ? cd : od;  mi[e] = sw ? ci : oi;
                cd    = sw ? od : cd;  ci    = sw ? oi : ci;
            }
        }
    }

    const size_t ob = (size_t)g * KK;
#pragma unroll
    for (int e = 0; e < KK; ++e) {
        out[ob + e] = mi[e];                                  // nn_idx
        out[(size_t)NROWS * KK + ob + e] = i;                 // center_idx
    }
}

extern "C" void kernel_launch(void* const* d_in, const int* in_sizes, int n_in,
                              void* d_out, int out_size, void* d_ws, size_t ws_size,
                              hipStream_t stream) {
    const float* x = (const float*)d_in[0];
    int* out = (int*)d_out;

    const size_t S_BYTES  = 65536;                           // s: 16384 f32
    const size_t XT_BYTES = (size_t)NROWS * NDIM * 4;        // 4 MB

    int js = 16;
    while (js > 1) {
        size_t need = S_BYTES + XT_BYTES + (size_t)NROWS * js * KK * 8;
        if (need <= ws_size) break;
        js >>= 1;
    }
    float* s   = (float*)d_ws;
    float* xTp = (float*)((char*)d_ws + S_BYTES);
    float* wd  = (float*)((char*)d_ws + S_BYTES + XT_BYTES);
    int*   wi  = (int*)((char*)d_ws + S_BYTES + XT_BYTES + (size_t)NROWS * js * KK * 4);
    const int jlen = NPTS / js;

    k_prep <<<NROWS / 256, 256, 0, stream>>>(x, s, xTp);
    k_main <<<NB * js * 32, 256, 0, stream>>>(x, xTp, s, wd, wi, js, jlen);
    k_merge<<<NROWS / 256, 256, 0, stream>>>(wd, wi, out, js);
}

// Round 7
// 870.077 us; speedup vs baseline: 3.8414x; 1.2890x over previous
//
#include <hip/hip_runtime.h>
#include <cfloat>
#include <climits>

#define NPTS 8192
#define NDIM 64
#define NB   2
#define KK   16
#define NROWS (NB * NPTS)

typedef float f2 __attribute__((ext_vector_type(2)));

// ---------- numpy f32 sum model: AVX512 pairwise(64) + reduce_add tree ----
__device__ __forceinline__ float np_sum64(const float* v) {
#pragma clang fp contract(off)
    float L[16], M[8], P[4];
#pragma unroll
    for (int l = 0; l < 16; ++l)
        L[l] = __fadd_rn(__fadd_rn(v[l], v[16 + l]), __fadd_rn(v[32 + l], v[48 + l]));
#pragma unroll
    for (int l = 0; l < 8; ++l) M[l] = __fadd_rn(L[l], L[l + 8]);
#pragma unroll
    for (int l = 0; l < 4; ++l) P[l] = __fadd_rn(M[l], M[l + 4]);
    return __fadd_rn(__fadd_rn(P[0], P[2]), __fadd_rn(P[1], P[3]));
}

// ---------- prep: s[] via np model; xTp pair-interleaved transpose --------
// element (n, c) at (n&~1)*64 + 2*c + (n&1). As an f2 array this is
// xTp2[(n>>1)*64 + c] = (x[c][n&~1], x[c][n|1]) -> candidate-pair per dim.
__global__ __launch_bounds__(256) void k_prep(const float* __restrict__ x,
                                              float* __restrict__ s,
                                              float* __restrict__ xTp) {
#pragma clang fp contract(off)
    int g = blockIdx.x * 256 + threadIdx.x;       // 0 .. NROWS-1
    int b = g / NPTS, n = g % NPTS;
    const float* xb = x + (size_t)b * NDIM * NPTS + n;
    float a[NDIM], v[NDIM];
#pragma unroll
    for (int c = 0; c < NDIM; ++c) {
        a[c] = xb[(size_t)c * NPTS];
        v[c] = __fmul_rn(a[c], a[c]);
    }
    s[g] = np_sum64(v);
    float* dst = xTp + ((size_t)(b * NPTS + (n & ~1))) * NDIM + (n & 1);
#pragma unroll
    for (int c = 0; c < NDIM; ++c) dst[2 * c] = a[c];
}

// pk helpers: IEEE-RN elementwise packed f32 (VOP3P). op_sel broadcasts
// the chosen half of src0 to both output elements.
__device__ __forceinline__ f2 pk_mul_blo(f2 a, f2 b) {   // {a.x*b.x, a.x*b.y}
    f2 t;
    asm("v_pk_mul_f32 %0, %1, %2 op_sel:[0,0] op_sel_hi:[0,1]"
        : "=v"(t) : "v"(a), "v"(b));
    return t;
}
__device__ __forceinline__ f2 pk_mul_bhi(f2 a, f2 b) {   // {a.y*b.x, a.y*b.y}
    f2 t;
    asm("v_pk_mul_f32 %0, %1, %2 op_sel:[1,0] op_sel_hi:[1,1]"
        : "=v"(t) : "v"(a), "v"(b));
    return t;
}
__device__ __forceinline__ void pk_acc(f2& A, f2 t) {    // A += t (elementwise)
    asm("v_pk_add_f32 %0, %0, %1" : "+v"(A) : "v"(t));
}
__device__ __forceinline__ f2 pk_mul_pl(f2 a, f2 b) {    // elementwise mul
    f2 t;
    asm("v_pk_mul_f32 %0, %1, %2" : "=v"(t) : "v"(a), "v"(b));
    return t;
}
__device__ __forceinline__ f2 pk_add_pl(f2 a, f2 b) {    // elementwise add
    f2 t;
    asm("v_pk_add_f32 %0, %1, %2" : "=v"(t) : "v"(a), "v"(b));
    return t;
}

// ---------- main: LDS-broadcast B-tiles + pk dots + deferred selection ----
// __launch_bounds__(256, 1): VGPR budget 512 -> the ~130-reg working set
// (a2[32] f2 + ld/li + temps) stays in registers. R3/R5/R6 all spilled
// (VGPR 72-112) and all showed the SAME 625 us VALU-issue time: scratch
// reloads + marshaling movs swamped every codegen improvement.
__global__ __launch_bounds__(256, 1) void k_main(const float* __restrict__ x,
                                                 const float* __restrict__ xTp,
                                                 const float* __restrict__ s,
                                                 float* __restrict__ wd,
                                                 int* __restrict__ wi,
                                                 int js, int jlen) {
#pragma clang fp contract(off)
    const int tid = threadIdx.x;

    // XCD-aware mapping: all 32 itile-blocks of one (b,chunk) group on one
    // XCD -> its 128 KB xTp slice is L2-resident there.
    const int ngroups = NB * js;
    int group, itile;
    if ((ngroups & 7) == 0) {
        const int gpx  = ngroups >> 3;
        const int xcd  = blockIdx.x & 7;
        const int slot = blockIdx.x >> 3;
        group = xcd * gpx + (slot >> 5);
        itile = slot & 31;
    } else {
        group = blockIdx.x >> 5;
        itile = blockIdx.x & 31;
    }
    const int b     = group / js;
    const int chunk = group - b * js;
    const int i     = itile * 256 + tid;
    const int boff  = b * NPTS;

    __shared__ f2     Bt[32 * 64];   // [pair p][dim c] f2 = cands (2p,2p+1); 16 KB
    __shared__ float  ss[64];        // s-values of the tile
    __shared__ float2 buf[8 * 257];  // deferred-candidate buffer; 16.4 KB

    const float* xb = x + (size_t)b * NDIM * NPTS + i;
    f2 a2[NDIM / 2];                 // {a[2q], a[2q+1]} dim-pairs, 64 VGPRs
#pragma unroll
    for (int q = 0; q < NDIM / 2; ++q) {
        a2[q].x = xb[(size_t)(2 * q) * NPTS];
        a2[q].y = xb[(size_t)(2 * q + 1) * NPTS];
    }
    const float sif = s[boff + i];
    const f2 si2 = {sif, sif};
    const f2 m2  = {-2.0f, -2.0f};

    float ld[KK]; int li[KK];
#pragma unroll
    for (int e = 0; e < KK; ++e) { ld[e] = FLT_MAX; li[e] = INT_MAX; }
    float ldL = FLT_MAX;
    int   cnt = 0;

    const int j0 = chunk * jlen;
    for (int jt = 0; jt < jlen; jt += 64) {       // one 64-cand LDS tile
        __syncthreads();
        {   // stage Bt: 16 KB contiguous copy of xTp f2 region (coalesced)
            const float4* src = (const float4*)(xTp + (size_t)(boff + j0 + jt) * NDIM);
            float4* dstv = (float4*)Bt;
#pragma unroll
            for (int t4 = 0; t4 < 4; ++t4) dstv[t4 * 256 + tid] = src[t4 * 256 + tid];
            if (tid < 16) ((float4*)ss)[tid] = ((const float4*)(s + boff + j0 + jt))[tid];
        }
        __syncthreads();

#pragma unroll 1
        for (int pw = 0; pw < 8; ++pw) {          // window = 4 pairs = 8 cands
#pragma unroll
            for (int pp = 0; pp < 4; ++pp) {
                const int p = pw * 4 + pp;
                const float4* bq = (const float4*)&Bt[p * 64];  // wave-uniform
                f2 A = {0.f, 0.f};
#pragma unroll
                for (int q = 0; q < NDIM / 2; ++q) {
                    float4 B01 = bq[q];           // dims 2q,2q+1 of the pair
                    f2 B0 = {B01.x, B01.y};
                    f2 B1 = {B01.z, B01.w};
                    pk_acc(A, pk_mul_blo(a2[q], B0));   // c = 2q
                    pk_acc(A, pk_mul_bhi(a2[q], B1));   // c = 2q+1
                }
                // D = (si + (-2*dot)) + s_j   (x-2 exact; adds RN; bit-exact)
                f2 sj = ((const f2*)ss)[p];
                f2 D  = pk_add_pl(pk_add_pl(si2, pk_mul_pl(m2, A)), sj);
                const int j = j0 + jt + 2 * p;
                // strict <: equal-d later-j loses (stable); push ascending-j
                if (D.x < ldL) { buf[cnt * 257 + tid] = make_float2(D.x, __int_as_float(j));     cnt++; }
                if (D.y < ldL) { buf[cnt * 257 + tid] = make_float2(D.y, __int_as_float(j + 1)); cnt++; }
            }
            // drain buffered candidates in push (= ascending-j) order
            if (__any(cnt > 0)) {
                for (int k = 0; k < cnt; ++k) {
                    float2 e = buf[k * 257 + tid];
                    float cd = e.x; int ci = __float_as_int(e.y);
                    if (cd < ldL) {
#pragma unroll
                        for (int t = 0; t < KK; ++t) {
                            bool sw = cd < ld[t];
                            float od = ld[t]; int oi = li[t];
                            ld[t] = sw ? cd : od;  li[t] = sw ? ci : oi;
                            cd    = sw ? od : cd;  ci    = sw ? oi : ci;
                        }
                        ldL = ld[KK - 1];
                    }
                }
                cnt = 0;
            }
        }
    }

    // transposed write: entry e of row g at wd[(chunk*16+e)*NROWS+g] (coalesced)
    const int gg = boff + i;
#pragma unroll
    for (int e = 0; e < KK; ++e) {
        wd[(size_t)(chunk * KK + e) * NROWS + gg] = ld[e];
        wi[(size_t)(chunk * KK + e) * NROWS + gg] = li[e];
    }
}

// ---------- merge chunks by (d, idx) lex, write outputs --------------------
__global__ __launch_bounds__(256) void k_merge(const float* __restrict__ wd,
                                               const int* __restrict__ wi,
                                               int* __restrict__ out,
                                               int js) {
    int g = blockIdx.x * 256 + threadIdx.x;   // 0 .. NROWS-1
    int i = g % NPTS;

    float md[KK]; int mi[KK];
#pragma unroll
    for (int e = 0; e < KK; ++e) { md[e] = FLT_MAX; mi[e] = INT_MAX; }

    const int tot = js * KK;
    for (int t = 0; t < tot; ++t) {
        float d  = wd[(size_t)t * NROWS + g];
        int   ix = wi[(size_t)t * NROWS + g];
        bool better = (d < md[KK - 1]) || (d == md[KK - 1] && ix < mi[KK - 1]);
        if (better) {
            float cd = d; int ci = ix;
#pragma unroll
            for (int e = 0; e < KK; ++e) {
                bool sw = (cd < md[e]) || (cd == md[e] && ci < mi[e]);
                float od = md[e]; int oi = mi[e];
                md[e] = sw ? cd : od;  mi[e] = sw ? ci : oi;
                cd    = sw ? od : cd;  ci    = sw ? oi : ci;
            }
        }
    }

    const size_t ob = (size_t)g * KK;
#pragma unroll
    for (int e = 0; e < KK; ++e) {
        out[ob + e] = mi[e];                                  // nn_idx
        out[(size_t)NROWS * KK + ob + e] = i;                 // center_idx
    }
}

extern "C" void kernel_launch(void* const* d_in, const int* in_sizes, int n_in,
                              void* d_out, int out_size, void* d_ws, size_t ws_size,
                              hipStream_t stream) {
    const float* x = (const float*)d_in[0];
    int* out = (int*)d_out;

    const size_t S_BYTES  = 65536;                           // s: 16384 f32
    const size_t XT_BYTES = (size_t)NROWS * NDIM * 4;        // 4 MB

    int js = 16;
    while (js > 1) {
        size_t need = S_BYTES + XT_BYTES + (size_t)NROWS * js * KK * 8;
        if (need <= ws_size) break;
        js >>= 1;
    }
    float* s   = (float*)d_ws;
    float* xTp = (float*)((char*)d_ws + S_BYTES);
    float* wd  = (float*)((char*)d_ws + S_BYTES + XT_BYTES);
    int*   wi  = (int*)((char*)d_ws + S_BYTES + XT_BYTES + (size_t)NROWS * js * KK * 4);
    const int jlen = NPTS / js;

    k_prep <<<NROWS / 256, 256, 0, stream>>>(x, s, xTp);
    k_main <<<NB * js * 32, 256, 0, stream>>>(x, xTp, s, wd, wi, js, jlen);
    k_merge<<<NROWS / 256, 256, 0, stream>>>(wd, wi, out, js);
}

// Round 9
// 834.142 us; speedup vs baseline: 4.0069x; 1.0431x over previous
//
#include <hip/hip_runtime.h>
#include <cfloat>
#include <climits>

#define NPTS 8192
#define NDIM 64
#define NB   2
#define KK   16
#define NROWS (NB * NPTS)
#define JS   8

typedef float f2 __attribute__((ext_vector_type(2)));

// ---------- numpy f32 sum model: AVX512 pairwise(64) + reduce_add tree ----
__device__ __forceinline__ float np_sum64(const float* v) {
#pragma clang fp contract(off)
    float L[16], M[8], P[4];
#pragma unroll
    for (int l = 0; l < 16; ++l)
        L[l] = __fadd_rn(__fadd_rn(v[l], v[16 + l]), __fadd_rn(v[32 + l], v[48 + l]));
#pragma unroll
    for (int l = 0; l < 8; ++l) M[l] = __fadd_rn(L[l], L[l + 8]);
#pragma unroll
    for (int l = 0; l < 4; ++l) P[l] = __fadd_rn(M[l], M[l + 4]);
    return __fadd_rn(__fadd_rn(P[0], P[2]), __fadd_rn(P[1], P[3]));
}

// ---------- prep: s[] via np model; xTp pair-interleaved transpose --------
// element (n, c) at (n&~1)*64 + 2*c + (n&1): f2 view gives candidate-pair
// (x[c][2p], x[c][2p+1]) per dim c.
__global__ __launch_bounds__(256) void k_prep(const float* __restrict__ x,
                                              float* __restrict__ s,
                                              float* __restrict__ xTp) {
#pragma clang fp contract(off)
    int g = blockIdx.x * 256 + threadIdx.x;       // 0 .. NROWS-1
    int b = g / NPTS, n = g % NPTS;
    const float* xb = x + (size_t)b * NDIM * NPTS + n;
    float a[NDIM], v[NDIM];
#pragma unroll
    for (int c = 0; c < NDIM; ++c) {
        a[c] = xb[(size_t)c * NPTS];
        v[c] = __fmul_rn(a[c], a[c]);
    }
    s[g] = np_sum64(v);
    float* dst = xTp + ((size_t)(b * NPTS + (n & ~1))) * NDIM + (n & 1);
#pragma unroll
    for (int c = 0; c < NDIM; ++c) dst[2 * c] = a[c];
}

// pk helpers: IEEE-RN elementwise packed f32 (VOP3P), HW-verified bit-exact
// in R6/R7 (absmax 0). op_sel broadcasts the chosen half of src0.
__device__ __forceinline__ f2 pk_mul_blo(f2 a, f2 b) {   // {a.x*b.x, a.x*b.y}
    f2 t;
    asm("v_pk_mul_f32 %0, %1, %2 op_sel:[0,0] op_sel_hi:[0,1]"
        : "=v"(t) : "v"(a), "v"(b));
    return t;
}
__device__ __forceinline__ f2 pk_mul_bhi(f2 a, f2 b) {   // {a.y*b.x, a.y*b.y}
    f2 t;
    asm("v_pk_mul_f32 %0, %1, %2 op_sel:[1,0] op_sel_hi:[1,1]"
        : "=v"(t) : "v"(a), "v"(b));
    return t;
}
__device__ __forceinline__ void pk_acc(f2& A, f2 t) {    // A += t (elementwise)
    asm("v_pk_add_f32 %0, %0, %1" : "+v"(A) : "v"(t));
}
__device__ __forceinline__ f2 pk_mul_pl(f2 a, f2 b) {
    f2 t;
    asm("v_pk_mul_f32 %0, %1, %2" : "=v"(t) : "v"(a), "v"(b));
    return t;
}
__device__ __forceinline__ f2 pk_add_pl(f2 a, f2 b) {
    f2 t;
    asm("v_pk_add_f32 %0, %1, %2" : "=v"(t) : "v"(a), "v"(b));
    return t;
}

// ---------- main: LDS-broadcast B-tiles + pk dots + deferred selection ----
// The R3-R7 plateau was regalloc refusing to keep the 64-VGPR row resident
// (VGPR_Count 72-112 every round; spill or remat-from-global). Fixes:
// amdgpu_waves_per_eu(1,2) sets the allocator's budget range explicitly;
// the row is 32 NAMED f2 locals (no arrays) pinned by opaque asm defs so
// rematerialization is impossible.
#define ROW_DECL(q) f2 a2_##q;
#define ROW_LOAD(q) do { \
        a2_##q.x = xb[(size_t)(2 * q) * NPTS]; \
        a2_##q.y = xb[(size_t)(2 * q + 1) * NPTS]; \
        asm("" : "+v"(a2_##q)); \
    } while (0);
#define DOT_STEP(q) do { \
        float4 B01 = bq[q]; \
        f2 B0 = {B01.x, B01.y}; \
        f2 B1 = {B01.z, B01.w}; \
        pk_acc(A, pk_mul_blo(a2_##q, B0));   /* c = 2q   */ \
        pk_acc(A, pk_mul_bhi(a2_##q, B1));   /* c = 2q+1 */ \
    } while (0);
#define REP32(M) M(0) M(1) M(2) M(3) M(4) M(5) M(6) M(7) \
                 M(8) M(9) M(10) M(11) M(12) M(13) M(14) M(15) \
                 M(16) M(17) M(18) M(19) M(20) M(21) M(22) M(23) \
                 M(24) M(25) M(26) M(27) M(28) M(29) M(30) M(31)

__global__ __launch_bounds__(256)
__attribute__((amdgpu_waves_per_eu(1, 2)))
void k_main(const float* __restrict__ x,
            const float* __restrict__ xTp,
            const float* __restrict__ s,
            float* __restrict__ wd,
            int* __restrict__ wi) {
#pragma clang fp contract(off)
    const int tid = threadIdx.x;

    // XCD-aware mapping: all 32 itile-blocks of one (b,chunk) group on one
    // XCD -> its 128 KB xTp slice is L2-resident there. ngroups=16, %8==0.
    const int gpx  = (NB * JS) >> 3;
    const int xcd  = blockIdx.x & 7;
    const int slot = blockIdx.x >> 3;
    const int group = xcd * gpx + (slot >> 5);
    const int itile = slot & 31;
    const int b     = group / JS;
    const int chunk = group - b * JS;
    const int i     = itile * 256 + tid;
    const int boff  = b * NPTS;
    const int jlen  = NPTS / JS;

    __shared__ f2     Bt[32 * 64];   // [pair p][dim c]; 16 KB
    __shared__ float  ss[64];
    __shared__ float2 buf[8 * 257];  // deferred-candidate buffer; 16.4 KB

    const float* xb = x + (size_t)b * NDIM * NPTS + i;
    REP32(ROW_DECL)
    REP32(ROW_LOAD)
    const float sif = s[boff + i];
    const f2 si2 = {sif, sif};
    const f2 m2  = {-2.0f, -2.0f};

    float ld[KK]; int li[KK];
#pragma unroll
    for (int e = 0; e < KK; ++e) { ld[e] = FLT_MAX; li[e] = INT_MAX; }
    float ldL = FLT_MAX;
    int   cnt = 0;

    const int j0 = chunk * jlen;
    for (int jt = 0; jt < jlen; jt += 64) {       // one 64-cand LDS tile
        __syncthreads();
        {   // stage Bt: 16 KB contiguous coalesced copy of xTp f2 region
            const float4* src = (const float4*)(xTp + (size_t)(boff + j0 + jt) * NDIM);
            float4* dstv = (float4*)Bt;
#pragma unroll
            for (int t4 = 0; t4 < 4; ++t4) dstv[t4 * 256 + tid] = src[t4 * 256 + tid];
            if (tid < 16) ((float4*)ss)[tid] = ((const float4*)(s + boff + j0 + jt))[tid];
        }
        __syncthreads();

#pragma unroll 1
        for (int pw = 0; pw < 8; ++pw) {          // window = 4 pairs = 8 cands
#pragma unroll
            for (int pp = 0; pp < 4; ++pp) {
                const int p = pw * 4 + pp;
                const float4* bq = (const float4*)&Bt[p * 64];  // wave-uniform
                f2 A = {0.f, 0.f};
                REP32(DOT_STEP)
                // D = (si + (-2*dot)) + s_j  (x-2 exact; adds RN; bit-exact)
                f2 sj = ((const f2*)ss)[p];
                f2 D  = pk_add_pl(pk_add_pl(si2, pk_mul_pl(m2, A)), sj);
                const int j = j0 + jt + 2 * p;
                // strict <: equal-d later-j loses (stable); push ascending-j
                if (D.x < ldL) { buf[cnt * 257 + tid] = make_float2(D.x, __int_as_float(j));     cnt++; }
                if (D.y < ldL) { buf[cnt * 257 + tid] = make_float2(D.y, __int_as_float(j + 1)); cnt++; }
            }
            // drain buffered candidates in push (= ascending-j) order
            if (__any(cnt > 0)) {
                for (int k = 0; k < cnt; ++k) {
                    float2 e = buf[k * 257 + tid];
                    float cd = e.x; int ci = __float_as_int(e.y);
                    if (cd < ldL) {
#pragma unroll
                        for (int t = 0; t < KK; ++t) {
                            bool sw = cd < ld[t];
                            float od = ld[t]; int oi = li[t];
                            ld[t] = sw ? cd : od;  li[t] = sw ? ci : oi;
                            cd    = sw ? od : cd;  ci    = sw ? oi : ci;
                        }
                        ldL = ld[KK - 1];
                    }
                }
                cnt = 0;
            }
        }
    }

    // transposed write: entry e of row g at wd[(chunk*16+e)*NROWS+g] (coalesced)
    const int gg = boff + i;
#pragma unroll
    for (int e = 0; e < KK; ++e) {
        wd[(size_t)(chunk * KK + e) * NROWS + gg] = ld[e];
        wi[(size_t)(chunk * KK + e) * NROWS + gg] = li[e];
    }
}

// ---------- merge chunks by (d, idx) lex, write outputs --------------------
__global__ __launch_bounds__(256) void k_merge(const float* __restrict__ wd,
                                               const int* __restrict__ wi,
                                               int* __restrict__ out) {
    int g = blockIdx.x * 256 + threadIdx.x;   // 0 .. NROWS-1
    int i = g % NPTS;

    float md[KK]; int mi[KK];
#pragma unroll
    for (int e = 0; e < KK; ++e) { md[e] = FLT_MAX; mi[e] = INT_MAX; }

    const int tot = JS * KK;
    for (int t = 0; t < tot; ++t) {
        float d  = wd[(size_t)t * NROWS + g];
        int   ix = wi[(size_t)t * NROWS + g];
        bool better = (d < md[KK - 1]) || (d == md[KK - 1] && ix < mi[KK - 1]);
        if (better) {
            float cd = d; int ci = ix;
#pragma unroll
            for (int e = 0; e < KK; ++e) {
                bool sw = (cd < md[e]) || (cd == md[e] && ci < mi[e]);
                float od = md[e]; int oi = mi[e];
                md[e] = sw ? cd : od;  mi[e] = sw ? ci : oi;
                cd    = sw ? od : cd;  ci    = sw ? oi : ci;
            }
        }
    }

    const size_t ob = (size_t)g * KK;
#pragma unroll
    for (int e = 0; e < KK; ++e) {
        out[ob + e] = mi[e];                                  // nn_idx
        out[(size_t)NROWS * KK + ob + e] = i;                 // center_idx
    }
}

extern "C" void kernel_launch(void* const* d_in, const int* in_sizes, int n_in,
                              void* d_out, int out_size, void* d_ws, size_t ws_size,
                              hipStream_t stream) {
    const float* x = (const float*)d_in[0];
    int* out = (int*)d_out;

    const size_t S_BYTES  = 65536;                           // s: 16384 f32
    const size_t XT_BYTES = (size_t)NROWS * NDIM * 4;        // 4 MB

    float* s   = (float*)d_ws;
    float* xTp = (float*)((char*)d_ws + S_BYTES);
    float* wd  = (float*)((char*)d_ws + S_BYTES + XT_BYTES);
    int*   wi  = (int*)((char*)d_ws + S_BYTES + XT_BYTES + (size_t)NROWS * JS * KK * 4);

    k_prep <<<NROWS / 256, 256, 0, stream>>>(x, s, xTp);
    k_main <<<NB * JS * 32, 256, 0, stream>>>(x, xTp, s, wd, wi);
    k_merge<<<NROWS / 256, 256, 0, stream>>>(wd, wi, out);
}

// Round 10
// 828.475 us; speedup vs baseline: 4.0343x; 1.0068x over previous
//
#include <hip/hip_runtime.h>
#include <cfloat>
#include <climits>

#define NPTS 8192
#define NDIM 64
#define NB   2
#define KK   16
#define MM   18            // approx candidates kept per chunk (margin over 16)
#define NROWS (NB * NPTS)

typedef float f2 __attribute__((ext_vector_type(2)));

// ---------- numpy f32 sum model: AVX512 pairwise(64) + reduce_add tree ----
__device__ __forceinline__ float np_sum64(const float* v) {
#pragma clang fp contract(off)
    float L[16], M[8], P[4];
#pragma unroll
    for (int l = 0; l < 16; ++l)
        L[l] = __fadd_rn(__fadd_rn(v[l], v[16 + l]), __fadd_rn(v[32 + l], v[48 + l]));
#pragma unroll
    for (int l = 0; l < 8; ++l) M[l] = __fadd_rn(L[l], L[l + 8]);
#pragma unroll
    for (int l = 0; l < 4; ++l) P[l] = __fadd_rn(M[l], M[l + 4]);
    return __fadd_rn(__fadd_rn(P[0], P[2]), __fadd_rn(P[1], P[3]));
}

// ---------- prep: s[] via np model; xTp pair-interleaved transpose --------
// element (n, c) at (n&~1)*64 + 2*c + (n&1): f2 view gives candidate-pair
// (x[c][2p], x[c][2p+1]) per dim c.
__global__ __launch_bounds__(256) void k_prep(const float* __restrict__ x,
                                              float* __restrict__ s,
                                              float* __restrict__ xTp) {
#pragma clang fp contract(off)
    int g = blockIdx.x * 256 + threadIdx.x;       // 0 .. NROWS-1
    int b = g / NPTS, n = g % NPTS;
    const float* xb = x + (size_t)b * NDIM * NPTS + n;
    float a[NDIM], v[NDIM];
#pragma unroll
    for (int c = 0; c < NDIM; ++c) {
        a[c] = xb[(size_t)c * NPTS];
        v[c] = __fmul_rn(a[c], a[c]);
    }
    s[g] = np_sum64(v);
    float* dst = xTp + ((size_t)(b * NPTS + (n & ~1))) * NDIM + (n & 1);
#pragma unroll
    for (int c = 0; c < NDIM; ++c) dst[2 * c] = a[c];
}

// pk helpers (VOP3P). op_sel semantics HW-verified bit-exact in R6-R9 for
// the 2-src forms; fma extends with src2. Phase-1 is APPROX: fused fma ok.
__device__ __forceinline__ void pk_fma_blo(f2 a, f2 b, f2& C) { // C += a.x*b
    asm("v_pk_fma_f32 %0, %1, %2, %0 op_sel:[0,0,0] op_sel_hi:[0,1,1]"
        : "+v"(C) : "v"(a), "v"(b));
}
__device__ __forceinline__ void pk_fma_bhi(f2 a, f2 b, f2& C) { // C += a.y*b
    asm("v_pk_fma_f32 %0, %1, %2, %0 op_sel:[1,0,0] op_sel_hi:[1,1,1]"
        : "+v"(C) : "v"(a), "v"(b));
}
__device__ __forceinline__ f2 pk_fma_pl(f2 a, f2 b, f2 c) {     // a*b+c
    f2 t;
    asm("v_pk_fma_f32 %0, %1, %2, %3" : "=v"(t) : "v"(a), "v"(b), "v"(c));
    return t;
}
__device__ __forceinline__ f2 pk_add_pl(f2 a, f2 b) {
    f2 t;
    asm("v_pk_add_f32 %0, %1, %2" : "=v"(t) : "v"(a), "v"(b));
    return t;
}

// row kept as 32 NAMED f2 locals pinned by opaque asm (no remat/spill bait)
#define ROW_DECL(q) f2 a2_##q;
#define ROW_LOAD(q) do { \
        a2_##q.x = xb[(size_t)(2 * q) * NPTS]; \
        a2_##q.y = xb[(size_t)(2 * q + 1) * NPTS]; \
        asm("" : "+v"(a2_##q)); \
    } while (0);
#define FMA_STEP(q) do { \
        float4 B01 = bq[q]; \
        f2 B0 = {B01.x, B01.y}; \
        f2 B1 = {B01.z, B01.w}; \
        pk_fma_blo(a2_##q, B0, Aa);   /* dim 2q,   both cands */ \
        pk_fma_bhi(a2_##q, B1, Ab);   /* dim 2q+1, both cands */ \
    } while (0);
#define REP32(M) M(0) M(1) M(2) M(3) M(4) M(5) M(6) M(7) \
                 M(8) M(9) M(10) M(11) M(12) M(13) M(14) M(15) \
                 M(16) M(17) M(18) M(19) M(20) M(21) M(22) M(23) \
                 M(24) M(25) M(26) M(27) M(28) M(29) M(30) M(31)

// ---------- phase 1: APPROX pk_fma dots, per-chunk top-MM ------------------
// waves_per_eu(4,4): pins allocator budget (128 VGPR) AND runtime residency
// (4 blocks/CU) - R4/R9 showed the runtime honors declared waves/EU, and
// (1,2)-style hints were capping occupancy at 2 blocks/CU.
__global__ __launch_bounds__(256)
__attribute__((amdgpu_waves_per_eu(4, 4)))
void k_phase1(const float* __restrict__ x,
              const float* __restrict__ xTp,
              const float* __restrict__ s,
              float* __restrict__ wd,
              int* __restrict__ wi,
              int js, int jlen) {
    const int tid = threadIdx.x;

    // XCD-aware mapping: all 32 itile-blocks of one (b,chunk) group on one
    // XCD -> its xTp slice stays L2-resident there.
    const int ngroups = NB * js;
    int group, itile;
    if ((ngroups & 7) == 0) {
        const int gpx  = ngroups >> 3;
        const int xcd  = blockIdx.x & 7;
        const int slot = blockIdx.x >> 3;
        group = xcd * gpx + (slot >> 5);
        itile = slot & 31;
    } else {
        group = blockIdx.x >> 5;
        itile = blockIdx.x & 31;
    }
    const int b     = group / js;
    const int chunk = group - b * js;
    const int i     = itile * 256 + tid;
    const int boff  = b * NPTS;

    __shared__ f2     Bt[32 * 64];   // [pair p][dim c]; 16 KB
    __shared__ float  ss[64];
    __shared__ float2 buf[8 * 257];  // deferred-candidate buffer; 16.4 KB

    const float* xb = x + (size_t)b * NDIM * NPTS + i;
    REP32(ROW_DECL)
    REP32(ROW_LOAD)
    const float sif = s[boff + i];
    const f2 si2 = {sif, sif};
    const f2 m2  = {-2.0f, -2.0f};

    float ld[MM]; int li[MM];
#pragma unroll
    for (int e = 0; e < MM; ++e) { ld[e] = FLT_MAX; li[e] = INT_MAX; }
    float ldL = FLT_MAX;
    int   cnt = 0;

    const int j0 = chunk * jlen;
    for (int jt = 0; jt < jlen; jt += 64) {       // one 64-cand LDS tile
        __syncthreads();
        {   // stage Bt: 16 KB contiguous coalesced copy of xTp f2 region
            const float4* src = (const float4*)(xTp + (size_t)(boff + j0 + jt) * NDIM);
            float4* dstv = (float4*)Bt;
#pragma unroll
            for (int t4 = 0; t4 < 4; ++t4) dstv[t4 * 256 + tid] = src[t4 * 256 + tid];
            if (tid < 16) ((float4*)ss)[tid] = ((const float4*)(s + boff + j0 + jt))[tid];
        }
        __syncthreads();

#pragma unroll 1
        for (int pw = 0; pw < 8; ++pw) {          // window = 4 pairs = 8 cands
#pragma unroll
            for (int pp = 0; pp < 4; ++pp) {
                const int p = pw * 4 + pp;
                const float4* bq = (const float4*)&Bt[p * 64];  // wave-uniform
                f2 Aa = {0.f, 0.f}, Ab = {0.f, 0.f};            // 2 indep chains
                REP32(FMA_STEP)
                f2 A   = pk_add_pl(Aa, Ab);
                f2 sj  = ((const f2*)ss)[p];
                f2 sij = pk_add_pl(si2, sj);
                f2 D   = pk_fma_pl(m2, A, sij);   // approx d (margin covers it)
                const int j = j0 + jt + 2 * p;
                if (D.x < ldL) { buf[cnt * 257 + tid] = make_float2(D.x, __int_as_float(j));     cnt++; }
                if (D.y < ldL) { buf[cnt * 257 + tid] = make_float2(D.y, __int_as_float(j + 1)); cnt++; }
            }
            if (__any(cnt > 0)) {                 // drain in ascending-j order
                for (int k = 0; k < cnt; ++k) {
                    float2 e = buf[k * 257 + tid];
                    float cd = e.x; int ci = __float_as_int(e.y);
                    if (cd < ldL) {
#pragma unroll
                        for (int t = 0; t < MM; ++t) {
                            bool sw = cd < ld[t];
                            float od = ld[t]; int oi = li[t];
                            ld[t] = sw ? cd : od;  li[t] = sw ? ci : oi;
                            cd    = sw ? od : cd;  ci    = sw ? oi : ci;
                        }
                        ldL = ld[MM - 1];
                    }
                }
                cnt = 0;
            }
        }
    }

    const int gg = boff + i;                      // coalesced transposed write
#pragma unroll
    for (int e = 0; e < MM; ++e) {
        wd[(size_t)(chunk * MM + e) * NROWS + gg] = ld[e];
        wi[(size_t)(chunk * MM + e) * NROWS + gg] = li[e];
    }
}

// ---------- phase 2: merge approx -> exact np-chain re-rank -> out ---------
__global__ __launch_bounds__(256) void k_refine(const float* __restrict__ x,
                                                const float* __restrict__ s,
                                                const float* __restrict__ wd,
                                                const int* __restrict__ wi,
                                                int* __restrict__ out,
                                                int js) {
#pragma clang fp contract(off)
    const int g = blockIdx.x * 256 + threadIdx.x; // 0 .. NROWS-1
    const int b = g / NPTS, i = g % NPTS;
    const float* xb = x + (size_t)b * NDIM * NPTS;

    // merge js*MM approx entries by (d_approx, idx) lex to top-MM
    float md[MM]; int mi[MM];
#pragma unroll
    for (int e = 0; e < MM; ++e) { md[e] = FLT_MAX; mi[e] = INT_MAX; }
    const int tot = js * MM;
    for (int t = 0; t < tot; ++t) {
        float d  = wd[(size_t)t * NROWS + g];
        int   ix = wi[(size_t)t * NROWS + g];
        bool better = (d < md[MM - 1]) || (d == md[MM - 1] && ix < mi[MM - 1]);
        if (better) {
            float cd = d; int ci = ix;
#pragma unroll
            for (int e = 0; e < MM; ++e) {
                bool sw = (cd < md[e]) || (cd == md[e] && ci < mi[e]);
                float od = md[e]; int oi = mi[e];
                md[e] = sw ? cd : od;  mi[e] = sw ? ci : oi;
                cd    = sw ? od : cd;  ci    = sw ? oi : ci;
            }
        }
    }

    // exact np-chain dot for the MM survivors: ascending-c round(mul) then
    // round(add) per cand - bit-identical to the reference einsum (R3-proven)
    float dot[MM];
#pragma unroll
    for (int t = 0; t < MM; ++t) dot[t] = 0.f;
    for (int c = 0; c < NDIM; ++c) {
        const float* row = xb + (size_t)c * NPTS;
        float xic = row[i];
#pragma unroll
        for (int t = 0; t < MM; ++t)
            dot[t] = __fadd_rn(dot[t], __fmul_rn(xic, row[mi[t]]));
    }
    const float si = s[b * NPTS + i];
    float de[MM];
#pragma unroll
    for (int t = 0; t < MM; ++t)
        de[t] = __fadd_rn(__fadd_rn(si, __fmul_rn(-2.0f, dot[t])), s[b * NPTS + mi[t]]);

    // stable top-16 by (d_exact, idx)
    float fd[KK]; int fi[KK];
#pragma unroll
    for (int e = 0; e < KK; ++e) { fd[e] = FLT_MAX; fi[e] = INT_MAX; }
#pragma unroll
    for (int t = 0; t < MM; ++t) {
        float d = de[t]; int ix = mi[t];
        bool better = (d < fd[KK - 1]) || (d == fd[KK - 1] && ix < fi[KK - 1]);
        if (better) {
            float cd = d; int ci = ix;
#pragma unroll
            for (int e = 0; e < KK; ++e) {
                bool sw = (cd < fd[e]) || (cd == fd[e] && ci < fi[e]);
                float od = fd[e]; int oi = fi[e];
                fd[e] = sw ? cd : od;  fi[e] = sw ? ci : oi;
                cd    = sw ? od : cd;  ci    = sw ? oi : ci;
            }
        }
    }

    const size_t ob = (size_t)g * KK;
#pragma unroll
    for (int e = 0; e < KK; ++e) {
        out[ob + e] = fi[e];                                  // nn_idx
        out[(size_t)NROWS * KK + ob + e] = i;                 // center_idx
    }
}

extern "C" void kernel_launch(void* const* d_in, const int* in_sizes, int n_in,
                              void* d_out, int out_size, void* d_ws, size_t ws_size,
                              hipStream_t stream) {
    const float* x = (const float*)d_in[0];
    int* out = (int*)d_out;

    const size_t S_BYTES  = 65536;                           // s: 16384 f32
    const size_t XT_BYTES = (size_t)NROWS * NDIM * 4;        // 4 MB

    int js = 16;
    while (js > 1) {
        size_t need = S_BYTES + XT_BYTES + (size_t)NROWS * js * MM * 8;
        if (need <= ws_size) break;
        js >>= 1;
    }
    float* s   = (float*)d_ws;
    float* xTp = (float*)((char*)d_ws + S_BYTES);
    float* wd  = (float*)((char*)d_ws + S_BYTES + XT_BYTES);
    int*   wi  = (int*)((char*)d_ws + S_BYTES + XT_BYTES + (size_t)NROWS * js * MM * 4);
    const int jlen = NPTS / js;

    k_prep  <<<NROWS / 256, 256, 0, stream>>>(x, s, xTp);
    k_phase1<<<NB * js * 32, 256, 0, stream>>>(x, xTp, s, wd, wi, js, jlen);
    k_refine<<<NROWS / 256, 256, 0, stream>>>(x, s, wd, wi, out, js);
}